// Round 1
// baseline (2781.312 us; speedup 1.0000x reference)
//
#include <hip/hip_runtime.h>

// MeshPool / MeshUnion.rebuild_features
// fe: [B, C, E] f32, groups: [B, E] i32 in [0,T)  ->  out: [B, C, T] f32
// out[b][c][t] = mean_{e: groups[b][e]==t} fe[b][c][e]   (0 for empty groups)

#define B_ 32
#define C_ 512
#define E_ 18000
#define T_ 9000

// ---- pass 1: per-(b,t) occurrence counts via global atomics (tiny: 576K adds)
__global__ __launch_bounds__(256) void count_kernel(const int* __restrict__ groups,
                                                    int* __restrict__ counts) {
    int i = blockIdx.x * 256 + threadIdx.x;   // over B*E = 576000 (exact multiple of 256? 576000/256=2250 yes)
    if (i < B_ * E_) {
        int b = i / E_;
        int g = groups[i];
        atomicAdd(&counts[b * T_ + g], 1);
    }
}

// ---- pass 2: in-place counts(int) -> reciprocal(float). One thread per element,
// read-then-write same address: race-free, graph-replay-safe (memset re-zeroes first).
__global__ __launch_bounds__(256) void inv_kernel(int* __restrict__ counts) {
    int i = blockIdx.x * 256 + threadIdx.x;   // over B*T = 288000 (=1125*256)
    if (i < B_ * T_) {
        int c = counts[i];
        float r = 1.0f / fmaxf((float)c, 1.0f);
        ((float*)counts)[i] = r;
    }
}

// ---- pass 3: main pooling. One block per (b,c). Sums for all T groups live in
// LDS (36 KB -> 4 blocks/CU), accumulated with LDS float atomics; output row
// written coalesced as float4. Global traffic = exactly fe-read + out-write.
__global__ __launch_bounds__(256) void pool_kernel(const float* __restrict__ fe,
                                                   const int* __restrict__ groups,
                                                   const float* __restrict__ inv,
                                                   float* __restrict__ out) {
    __shared__ float sums[T_];                 // 9000 f32 = 36 KB
    const int c = blockIdx.x;
    const int b = blockIdx.y;

    // zero LDS accumulator
    for (int t = threadIdx.x; t < T_; t += 256) sums[t] = 0.0f;
    __syncthreads();

    const float4* fe4 = (const float4*)(fe + ((size_t)b * C_ + c) * E_);
    const int4*   g4  = (const int4*)(groups + (size_t)b * E_);

    // E/4 = 4500 float4 elements per row; coalesced 16B/lane reads.
    // groups row (72 KB) is shared by 512 blocks per batch -> L2-resident.
    for (int e4 = threadIdx.x; e4 < E_ / 4; e4 += 256) {
        float4 v = fe4[e4];
        int4   g = g4[e4];
        atomicAdd(&sums[g.x], v.x);
        atomicAdd(&sums[g.y], v.y);
        atomicAdd(&sums[g.z], v.z);
        atomicAdd(&sums[g.w], v.w);
    }
    __syncthreads();

    // write out[b][c][:] = sums * inv[b][:], vectorized (T/4 = 2250)
    const float4* inv4 = (const float4*)(inv + (size_t)b * T_);
    float4*       out4 = (float4*)(out + ((size_t)b * C_ + c) * T_);
    const float4* s4   = (const float4*)sums;
    for (int t4 = threadIdx.x; t4 < T_ / 4; t4 += 256) {
        float4 s  = s4[t4];
        float4 iv = inv4[t4];
        float4 o;
        o.x = s.x * iv.x;
        o.y = s.y * iv.y;
        o.z = s.z * iv.z;
        o.w = s.w * iv.w;
        out4[t4] = o;
    }
}

extern "C" void kernel_launch(void* const* d_in, const int* in_sizes, int n_in,
                              void* d_out, int out_size, void* d_ws, size_t ws_size,
                              hipStream_t stream) {
    const float* fe     = (const float*)d_in[0];   // [B, C, E] f32
    const int*   groups = (const int*)d_in[1];     // [B, E] i32
    float*       out    = (float*)d_out;           // [B, C, T] f32

    int* counts = (int*)d_ws;                      // B*T ints = 1.152 MB, reused as float inv

    // ws is re-poisoned to 0xAA before every timed call -> must re-zero counts each call
    hipMemsetAsync(counts, 0, (size_t)B_ * T_ * sizeof(int), stream);

    count_kernel<<<(B_ * E_ + 255) / 256, 256, 0, stream>>>(groups, counts);
    inv_kernel<<<(B_ * T_ + 255) / 256, 256, 0, stream>>>(counts);

    dim3 grid(C_, B_);
    pool_kernel<<<grid, 256, 0, stream>>>(fe, groups, (const float*)counts, out);
}